// Round 14
// baseline (168.585 us; speedup 1.0000x reference)
//
#include <hip/hip_runtime.h>

typedef __attribute__((ext_vector_type(8))) short bf16x8;
typedef __attribute__((ext_vector_type(4))) float f32x4;
typedef __attribute__((ext_vector_type(4))) unsigned short u16x4;

#define HW_ 16384
#define LDSTR 144     // 72 bf16 elems * 2B per LDS row
#define TILEB 9216    // one 64-pixel x 64-channel bf16 tile
#define NTILES 4096
#define GRID 768      // 3 blocks/CU x 256 CUs; each block sweeps 5-6 tiles

__device__ __forceinline__ float bf2f(unsigned short u) {
  union { unsigned u; float f; } x; x.u = ((unsigned)u) << 16; return x.f;
}
__device__ __forceinline__ unsigned short f2bf(float f) {
  union { float f; unsigned u; } x; x.f = f;
  unsigned r = x.u + 0x7fffu + ((x.u >> 16) & 1u);
  return (unsigned short)(r >> 16);
}
// XOR-swizzled LDS byte offset for transposed tile xT[px][ch]
__device__ __forceinline__ int swz(int row, int cb) {
  return row * LDSTR + (cb ^ (((row >> 3) & 7) << 4));
}

#define MFMA(a, b, c) __builtin_amdgcn_mfma_f32_16x16x32_bf16(a, b, c, 0, 0, 0)

// (256,3): proven no-spill point (R9: forcing 4 waves/EU spills; R11: higher
// occupancy alone buys nothing). R14: persistent blocks pipeline the staging
// of tile n+GRID under the compute of tile n (T14 at tile scope), and load
// weights once per block instead of once per tile.
__global__ __launch_bounds__(256, 3) void gci_kernel(
    const float* __restrict__ x1, const float* __restrict__ x2,
    const float* __restrict__ x3, const float* __restrict__ x4,
    const float* __restrict__ wI, const float* __restrict__ bI,
    const float* __restrict__ wS, const float* __restrict__ bS,
    const float* __restrict__ wG, const float* __restrict__ bG,
    float* __restrict__ out)
{
  // 4 tiles of [64 px][72 bf16]: xT0..xT3 (36864 B)
  __shared__ __align__(16) char ldsb[4 * TILEB];

  const int t    = threadIdx.x;
  const int lane = t & 63;
  const int w    = t >> 6;       // wave id == output-channel group (16 ch)
  const int lr   = lane & 15;
  const int lg   = lane >> 4;

  const float* xin[4] = {x1, x2, x3, x4};

  // staging coordinates for this thread (fixed): 4 (c,p4) pairs
  int cc[4], pp[4];
  #pragma unroll
  for (int ch2 = 0; ch2 < 4; ++ch2) {
    const int q = ch2 * 256 + t;
    cc[ch2] = q >> 4;
    pp[ch2] = q & 15;
  }

  // ---------- weights: once per block (amortized over ~5 tiles) ----------
  bf16x8 fWi[2], fD[2], fG1[2], fG2[2];
  #pragma unroll
  for (int kk = 0; kk < 2; ++kk) {
    const int row = w * 16 + lr, col = kk * 32 + lg * 8;
    f32x4 wa = *(const f32x4*)(wI + row * 64 + col);
    f32x4 wb = *(const f32x4*)(wI + row * 64 + col + 4);
    f32x4 sa = *(const f32x4*)(wS + row * 64 + col);
    f32x4 sb = *(const f32x4*)(wS + row * 64 + col + 4);
    f32x4 ga = *(const f32x4*)(wG + row * 128 + col);
    f32x4 gb = *(const f32x4*)(wG + row * 128 + col + 4);
    f32x4 ha = *(const f32x4*)(wG + row * 128 + 64 + col);
    f32x4 hb = *(const f32x4*)(wG + row * 128 + 64 + col + 4);
    #pragma unroll
    for (int j = 0; j < 4; ++j) {
      fWi[kk][j]     = (short)f2bf(wa[j]);
      fWi[kk][j + 4] = (short)f2bf(wb[j]);
      fD[kk][j]      = (short)f2bf(sa[j] - wa[j]);
      fD[kk][j + 4]  = (short)f2bf(sb[j] - wb[j]);
      fG1[kk][j]     = (short)f2bf(ga[j]);
      fG1[kk][j + 4] = (short)f2bf(gb[j]);
      fG2[kk][j]     = (short)f2bf(ha[j]);
      fG2[kk][j + 4] = (short)f2bf(hb[j]);
    }
  }
  f32x4 biasA0, biasG;
  #pragma unroll
  for (int r = 0; r < 4; ++r) {
    const int ch = w * 16 + lg * 4 + r;
    biasA0[r] = bS[ch] + 3.f * bI[ch];
    biasG[r]  = bG[ch];
  }

  // ---------- initial full stage of first tile ----------
  int tile = blockIdx.x;
  {
    const int pix0 = tile * 64;
    const int b    = pix0 >> 14;
    const int pimg = pix0 & (HW_ - 1);
    f32x4 v[16];
    #pragma unroll
    for (int ch2 = 0; ch2 < 4; ++ch2) {
      const int goff = (b * 64 + cc[ch2]) * HW_ + pimg + pp[ch2] * 4;
      #pragma unroll
      for (int i = 0; i < 4; ++i)
        v[ch2 * 4 + i] = *reinterpret_cast<const f32x4*>(xin[i] + goff);
    }
    #pragma unroll
    for (int ch2 = 0; ch2 < 4; ++ch2)
      #pragma unroll
      for (int i = 0; i < 4; ++i)
        #pragma unroll
        for (int j = 0; j < 4; ++j)
          *(unsigned short*)(ldsb + i * TILEB + swz(pp[ch2] * 4 + j, cc[ch2] * 2)) =
              f2bf(v[ch2 * 4 + i][j]);
  }
  __syncthreads();

  // ---------- persistent sweep ----------
  for (; tile < NTILES; tile += GRID) {
    const int pix0 = tile * 64;
    const int b    = pix0 >> 14;
    const int pimg = pix0 & (HW_ - 1);

    const int  nt   = tile + GRID;
    const bool hasN = nt < NTILES;
    const int  bn    = (nt * 64) >> 14;
    const int  pimgn = (nt * 64) & (HW_ - 1);

    // Abase[g] = Sum_i Wi*x_i + bias (tiles hold x data here)
    f32x4 Abase[4];
    #pragma unroll
    for (int g = 0; g < 4; ++g) {
      Abase[g] = biasA0;
      #pragma unroll
      for (int i = 0; i < 4; ++i) {
        #pragma unroll
        for (int kk = 0; kk < 2; ++kk) {
          bf16x8 f = *(const bf16x8*)(ldsb + i * TILEB + swz(g * 16 + lr, kk * 64 + lg * 16));
          Abase[g] = MFMA(fWi[kk], f, Abase[g]);
        }
      }
    }

    f32x4 vn[2][4];   // next-tile staging regs, ping-pong by tensor parity

    #pragma unroll
    for (int i = 0; i < 4; ++i) {
      char* tb = ldsb + i * TILEB;

      // x B-frags (held through gate) + residual pre-read
      bf16x8 xB[4][2];
      #pragma unroll
      for (int g = 0; g < 4; ++g)
        #pragma unroll
        for (int kk = 0; kk < 2; ++kk)
          xB[g][kk] = *(const bf16x8*)(tb + swz(g * 16 + lr, kk * 64 + lg * 16));
      unsigned xrp[8];
      #pragma unroll
      for (int j = 0; j < 8; ++j)
        xrp[j] = *(const unsigned*)(tb + swz(lane, w * 32 + 4 * j));

      // agg = relu(D * x_i + Abase)
      f32x4 agg[4];
      #pragma unroll
      for (int g = 0; g < 4; ++g) {
        agg[g] = Abase[g];
        #pragma unroll
        for (int kk = 0; kk < 2; ++kk) agg[g] = MFMA(fD[kk], xB[g][kk], agg[g]);
      }

      // issue next tile's loads for tensor i (consumed one tensor later)
      if (hasN) {
        #pragma unroll
        for (int ch2 = 0; ch2 < 4; ++ch2) {
          const int goffN = (bn * 64 + cc[ch2]) * HW_ + pimgn + pp[ch2] * 4;
          vn[i & 1][ch2] = *reinterpret_cast<const f32x4*>(xin[i] + goffN);
        }
      }

      __syncthreads();   // all waves done reading x-tile i (and gate i-1 done)

      // write relu(agg) bf16 over tile i
      #pragma unroll
      for (int g = 0; g < 4; ++g) {
        u16x4 pk;
        #pragma unroll
        for (int r = 0; r < 4; ++r) pk[r] = f2bf(fmaxf(agg[g][r], 0.f));
        *(u16x4*)(tb + swz(g * 16 + lr, w * 32 + lg * 8)) = pk;
      }
      // refill tile i-1 with next tile's x data (tile i-1 is dead now)
      if (hasN && i > 0) {
        char* pb = ldsb + (i - 1) * TILEB;
        #pragma unroll
        for (int ch2 = 0; ch2 < 4; ++ch2)
          #pragma unroll
          for (int j = 0; j < 4; ++j)
            *(unsigned short*)(pb + swz(pp[ch2] * 4 + j, cc[ch2] * 2)) =
                f2bf(vn[(i - 1) & 1][ch2][j]);
      }

      __syncthreads();   // aggT complete

      // gate: out = x + Wg1*x + Wg2*agg + b_gate
      f32x4 og[4];
      #pragma unroll
      for (int g = 0; g < 4; ++g) {
        bf16x8 aB[2];
        #pragma unroll
        for (int kk = 0; kk < 2; ++kk)
          aB[kk] = *(const bf16x8*)(tb + swz(g * 16 + lr, kk * 64 + lg * 16));
        og[g] = biasG;
        #pragma unroll
        for (int kk = 0; kk < 2; ++kk) {
          og[g] = MFMA(fG1[kk], xB[g][kk], og[g]);
          og[g] = MFMA(fG2[kk], aB[kk], og[g]);
        }
      }

      // butterfly 4x4 (lg <-> g) transpose
      float B[4][4];
      #pragma unroll
      for (int r = 0; r < 4; ++r) {
        float X0 = og[0][r], X1 = og[1][r], X2 = og[2][r], X3 = og[3][r];
        float s01 = (lg & 1) ? X0 : X1; s01 = __shfl_xor(s01, 16, 64);
        float n0  = (lg & 1) ? s01 : X0;
        float n1  = (lg & 1) ? X1  : s01;
        float s23 = (lg & 1) ? X2 : X3; s23 = __shfl_xor(s23, 16, 64);
        float n2  = (lg & 1) ? s23 : X2;
        float n3  = (lg & 1) ? X3  : s23;
        float u02 = (lg & 2) ? n0 : n2; u02 = __shfl_xor(u02, 32, 64);
        B[r][0]   = (lg & 2) ? u02 : n0;
        B[r][2]   = (lg & 2) ? n2  : u02;
        float u13 = (lg & 2) ? n1 : n3; u13 = __shfl_xor(u13, 32, 64);
        B[r][1]   = (lg & 2) ? u13 : n1;
        B[r][3]   = (lg & 2) ? n3  : u13;
      }

      // stores: one instruction = 64 consecutive px (256 B lines)
      const int obase0 = i * 16777216 + b * 64 * HW_ + pimg;
      #pragma unroll
      for (int c = 0; c < 16; ++c) {
        float vv = B[c & 3][c >> 2]
                 + bf2f((unsigned short)(xrp[c >> 1] >> ((c & 1) * 16)));
        out[obase0 + (w * 16 + c) * HW_ + lane] = vv;
      }
    }

    // refill tile 3 for next sweep iteration
    if (hasN) {
      __syncthreads();
      char* pb = ldsb + 3 * TILEB;
      #pragma unroll
      for (int ch2 = 0; ch2 < 4; ++ch2)
        #pragma unroll
        for (int j = 0; j < 4; ++j)
          *(unsigned short*)(pb + swz(pp[ch2] * 4 + j, cc[ch2] * 2)) =
              f2bf(vn[1][ch2][j]);
      __syncthreads();
    }
  }
}

extern "C" void kernel_launch(void* const* d_in, const int* in_sizes, int n_in,
                              void* d_out, int out_size, void* d_ws, size_t ws_size,
                              hipStream_t stream) {
  (void)in_sizes; (void)n_in; (void)d_ws; (void)ws_size; (void)out_size;
  gci_kernel<<<dim3(GRID), dim3(256), 0, stream>>>(
      (const float*)d_in[0], (const float*)d_in[1],
      (const float*)d_in[2], (const float*)d_in[3],
      (const float*)d_in[4], (const float*)d_in[5],
      (const float*)d_in[6], (const float*)d_in[7],
      (const float*)d_in[8], (const float*)d_in[9],
      (float*)d_out);
}

// Round 15
// 121.441 us; speedup vs baseline: 1.3882x; 1.3882x over previous
//
#include <hip/hip_runtime.h>

typedef __attribute__((ext_vector_type(8))) short bf16x8;
typedef __attribute__((ext_vector_type(4))) float f32x4;
typedef __attribute__((ext_vector_type(4))) unsigned short u16x4;

#define HW_ 16384
#define LDSTR 144     // 72 bf16 elems * 2B per LDS row
#define TILEB 9216    // one 64-pixel x 64-channel bf16 tile

__device__ __forceinline__ float bf2f(unsigned short u) {
  union { unsigned u; float f; } x; x.u = ((unsigned)u) << 16; return x.f;
}
__device__ __forceinline__ unsigned short f2bf(float f) {
  union { float f; unsigned u; } x; x.f = f;
  unsigned r = x.u + 0x7fffu + ((x.u >> 16) & 1u);
  return (unsigned short)(r >> 16);
}
// XOR-swizzled LDS byte offset for transposed tile xT[px][ch]
__device__ __forceinline__ int swz(int row, int cb) {
  return row * LDSTR + (cb ^ (((row >> 3) & 7) << 4));
}

#define MFMA(a, b, c) __builtin_amdgcn_mfma_f32_16x16x32_bf16(a, b, c, 0, 0, 0)

// (256,3): proven no-spill point (R9/R5: forcing 4 waves/EU spills; R11/R14:
// occupancy and pipeline restructures regress). R15: staging writes b64
// (thread = 4ch x 4px, in-lane repack) to kill the measured 12M-cycle
// LDS bank-conflict term. One grid block per 64-px tile (R14's persistent
// sweep destroyed L3 input residency: FETCH 138->212 MB).
__global__ __launch_bounds__(256, 3) void gci_kernel(
    const float* __restrict__ x1, const float* __restrict__ x2,
    const float* __restrict__ x3, const float* __restrict__ x4,
    const float* __restrict__ wI, const float* __restrict__ bI,
    const float* __restrict__ wS, const float* __restrict__ bS,
    const float* __restrict__ wG, const float* __restrict__ bG,
    float* __restrict__ out)
{
  // 4 tiles of [64 px][72 bf16]: xT0..xT3 (36864 B)
  __shared__ __align__(16) char ldsb[4 * TILEB];

  const int t    = threadIdx.x;
  const int lane = t & 63;
  const int w    = t >> 6;       // wave id == output-channel group (16 ch)
  const int lr   = lane & 15;
  const int lg   = lane >> 4;

  const int pix0 = blockIdx.x * 64;
  const int b    = pix0 >> 14;          // image index (HW = 16384)
  const int pimg = pix0 & (HW_ - 1);    // pixel offset within image

  const float* xin[4] = {x1, x2, x3, x4};

  // ---------- stage x1..x4 transposed (bf16) into LDS ----------
  // thread: 4 channels (c0..c0+3) x 4 px (pxg..pxg+3). Global per instr:
  // 4 x 256B contiguous segments (same as R13). LDS: 16 ds_write_b64 per
  // thread (was 64 ds_write_b16) — in-lane repack, no shuffles, ~2-way banks.
  {
    const int pxg = (t & 15) * 4;       // px base
    const int c0  = (t >> 4) * 4;       // channel base
    f32x4 v[16];
    #pragma unroll
    for (int i = 0; i < 4; ++i)
      #pragma unroll
      for (int d = 0; d < 4; ++d)
        v[i * 4 + d] = *reinterpret_cast<const f32x4*>(
            xin[i] + (b * 64 + c0 + d) * HW_ + pimg + pxg);
    #pragma unroll
    for (int i = 0; i < 4; ++i)
      #pragma unroll
      for (int j = 0; j < 4; ++j) {
        u16x4 pk;
        #pragma unroll
        for (int d = 0; d < 4; ++d) pk[d] = f2bf(v[i * 4 + d][j]);
        *(u16x4*)(ldsb + i * TILEB + swz(pxg + j, c0 * 2)) = pk;
      }
  }

  // ---------- this wave's weights: 16 output channels (rows w*16..+15) ----------
  // A-frag(kk): lane holds W[w*16 + lr][kk*32 + lg*8 + j], j=0..7
  bf16x8 fWi[2], fD[2], fG1[2], fG2[2];
  #pragma unroll
  for (int kk = 0; kk < 2; ++kk) {
    const int row = w * 16 + lr, col = kk * 32 + lg * 8;
    f32x4 wa = *(const f32x4*)(wI + row * 64 + col);
    f32x4 wb = *(const f32x4*)(wI + row * 64 + col + 4);
    f32x4 sa = *(const f32x4*)(wS + row * 64 + col);
    f32x4 sb = *(const f32x4*)(wS + row * 64 + col + 4);
    f32x4 ga = *(const f32x4*)(wG + row * 128 + col);
    f32x4 gb = *(const f32x4*)(wG + row * 128 + col + 4);
    f32x4 ha = *(const f32x4*)(wG + row * 128 + 64 + col);
    f32x4 hb = *(const f32x4*)(wG + row * 128 + 64 + col + 4);
    #pragma unroll
    for (int j = 0; j < 4; ++j) {
      fWi[kk][j]     = (short)f2bf(wa[j]);
      fWi[kk][j + 4] = (short)f2bf(wb[j]);
      fD[kk][j]      = (short)f2bf(sa[j] - wa[j]);
      fD[kk][j + 4]  = (short)f2bf(sb[j] - wb[j]);
      fG1[kk][j]     = (short)f2bf(ga[j]);
      fG1[kk][j + 4] = (short)f2bf(gb[j]);
      fG2[kk][j]     = (short)f2bf(ha[j]);
      fG2[kk][j + 4] = (short)f2bf(hb[j]);
    }
  }

  // biases: C/D row = lg*4 + r  ->  ch = w*16 + lg*4 + r
  f32x4 biasA0, biasG;
  #pragma unroll
  for (int r = 0; r < 4; ++r) {
    const int ch = w * 16 + lg * 4 + r;
    biasA0[r] = bS[ch] + 3.f * bI[ch];
    biasG[r]  = bG[ch];
  }

  __syncthreads();

  // ---------- Abase[g] = Sum_i Wi*x_i + bias, via MFMA ----------
  f32x4 Abase[4];
  #pragma unroll
  for (int g = 0; g < 4; ++g) {
    Abase[g] = biasA0;
    #pragma unroll
    for (int i = 0; i < 4; ++i) {
      #pragma unroll
      for (int kk = 0; kk < 2; ++kk) {
        bf16x8 f = *(const bf16x8*)(ldsb + i * TILEB + swz(g * 16 + lr, kk * 64 + lg * 16));
        Abase[g] = MFMA(fWi[kk], f, Abase[g]);
      }
    }
  }

  // ---------- per tensor: agg + gate + residual + store ----------
  #pragma unroll
  for (int i = 0; i < 4; ++i) {
    char* tb = ldsb + i * TILEB;

    // B-frags for all 4 px-groups (held across agg AND gate; tile is overwritten)
    bf16x8 xB[4][2];
    #pragma unroll
    for (int g = 0; g < 4; ++g)
      #pragma unroll
      for (int kk = 0; kk < 2; ++kk)
        xB[g][kk] = *(const bf16x8*)(tb + swz(g * 16 + lr, kk * 64 + lg * 16));

    // residual pre-read: lane = px, channels (w*16+2j, w*16+2j+1)
    unsigned xrp[8];
    #pragma unroll
    for (int j = 0; j < 8; ++j)
      xrp[j] = *(const unsigned*)(tb + swz(lane, w * 32 + 4 * j));

    // agg = relu(D * x_i + Abase)
    f32x4 agg[4];
    #pragma unroll
    for (int g = 0; g < 4; ++g) {
      agg[g] = Abase[g];
      #pragma unroll
      for (int kk = 0; kk < 2; ++kk) agg[g] = MFMA(fD[kk], xB[g][kk], agg[g]);
    }

    __syncthreads();   // all waves done reading x-tile i

    // write relu(agg) bf16 over tile i: our 16 ch columns, all px rows
    #pragma unroll
    for (int g = 0; g < 4; ++g) {
      u16x4 pk;
      #pragma unroll
      for (int r = 0; r < 4; ++r) pk[r] = f2bf(fmaxf(agg[g][r], 0.f));
      *(u16x4*)(tb + swz(g * 16 + lr, w * 32 + lg * 8)) = pk;
    }

    __syncthreads();   // aggT complete (all 64 channels)

    // gate: out = x + Wg1*x + Wg2*agg + b_gate
    f32x4 og[4];
    #pragma unroll
    for (int g = 0; g < 4; ++g) {
      bf16x8 aB[2];
      #pragma unroll
      for (int kk = 0; kk < 2; ++kk)
        aB[kk] = *(const bf16x8*)(tb + swz(g * 16 + lr, kk * 64 + lg * 16));
      og[g] = biasG;
      #pragma unroll
      for (int kk = 0; kk < 2; ++kk) {
        og[g] = MFMA(fG1[kk], xB[g][kk], og[g]);
        og[g] = MFMA(fG2[kk], aB[kk], og[g]);
      }
    }

    // ---- butterfly 4x4 (lg <-> g) transpose: B[r][v] at lane(lg,lr) =
    // og[lg][r] of lane(v,lr). 16 shfl_xor per tensor.
    float B[4][4];
    #pragma unroll
    for (int r = 0; r < 4; ++r) {
      float X0 = og[0][r], X1 = og[1][r], X2 = og[2][r], X3 = og[3][r];
      float s01 = (lg & 1) ? X0 : X1; s01 = __shfl_xor(s01, 16, 64);
      float n0  = (lg & 1) ? s01 : X0;
      float n1  = (lg & 1) ? X1  : s01;
      float s23 = (lg & 1) ? X2 : X3; s23 = __shfl_xor(s23, 16, 64);
      float n2  = (lg & 1) ? s23 : X2;
      float n3  = (lg & 1) ? X3  : s23;
      float u02 = (lg & 2) ? n0 : n2; u02 = __shfl_xor(u02, 32, 64);
      B[r][0]   = (lg & 2) ? u02 : n0;
      B[r][2]   = (lg & 2) ? n2  : u02;
      float u13 = (lg & 2) ? n1 : n3; u13 = __shfl_xor(u13, 32, 64);
      B[r][1]   = (lg & 2) ? u13 : n1;
      B[r][3]   = (lg & 2) ? n3  : u13;
    }

    // stores: one instruction = 64 consecutive px (256 B lines)
    const int obase0 = i * 16777216 + b * 64 * HW_ + pimg;
    #pragma unroll
    for (int c = 0; c < 16; ++c) {
      float vv = B[c & 3][c >> 2]
               + bf2f((unsigned short)(xrp[c >> 1] >> ((c & 1) * 16)));
      out[obase0 + (w * 16 + c) * HW_ + lane] = vv;
    }
  }
}

extern "C" void kernel_launch(void* const* d_in, const int* in_sizes, int n_in,
                              void* d_out, int out_size, void* d_ws, size_t ws_size,
                              hipStream_t stream) {
  (void)in_sizes; (void)n_in; (void)d_ws; (void)ws_size; (void)out_size;
  gci_kernel<<<dim3(4096), dim3(256), 0, stream>>>(
      (const float*)d_in[0], (const float*)d_in[1],
      (const float*)d_in[2], (const float*)d_in[3],
      (const float*)d_in[4], (const float*)d_in[5],
      (const float*)d_in[6], (const float*)d_in[7],
      (const float*)d_in[8], (const float*)d_in[9],
      (float*)d_out);
}